// Round 1
// baseline (425.849 us; speedup 1.0000x reference)
//
#include <hip/hip_runtime.h>
#include <math.h>

#define Bdim 8
#define Sdim 1024
#define Hdim 1024
#define NHd 16
#define HDd 64
#define N3H 3072

// ws layout (ushort elements)
// Q: [bh][s][128] row-major (hi|lo). K: [bh][16 tiles][8192] fragment-ordered.
// V: [bh][16 tiles][4096] fragment-ordered. W^T hi/lo planes after.
#define Q_OFF   0u
#define K_OFF   16777216u
#define V_OFF   33554432u
#define WH_OFF  41943040u
#define WL_OFF  45088768u
// d_out scratch layout (ushort elements): Ahi, Alo
#define AHI_OFF 0u
#define ALO_OFF 8388608u

typedef __bf16 bf16x8 __attribute__((ext_vector_type(8)));
typedef float  f32x4  __attribute__((ext_vector_type(4)));

__device__ __forceinline__ unsigned short f2bf(float x) {
  unsigned b = __builtin_bit_cast(unsigned, x);
  return (unsigned short)((b + 0x7FFFu + ((b >> 16) & 1u)) >> 16);
}
__device__ __forceinline__ float bf2f(unsigned short h) {
  unsigned b = ((unsigned)h) << 16;
  return __builtin_bit_cast(float, b);
}
__device__ __forceinline__ void split_hl(float v, unsigned short& h, unsigned short& l) {
  h = f2bf(v);
  l = f2bf(v - bf2f(h));
}
__device__ __forceinline__ void async16(void* lds, const void* g) {
  __builtin_amdgcn_global_load_lds((const __attribute__((address_space(1))) unsigned int*)g,
                                   (__attribute__((address_space(3))) unsigned int*)lds, 16, 0, 0);
}

// ---------- fused convert: A -> hi/lo planes (d_out scratch); W -> W^T hi/lo (ws) ----------
__global__ __launch_bounds__(256) void convert_AW(
    const float* __restrict__ A, const float* __restrict__ W,
    unsigned short* __restrict__ aout, unsigned short* __restrict__ ws)
{
  __shared__ float T[64][65];
  const int tid = threadIdx.x;
  int bid = blockIdx.x;
  if (bid < 4096) {
    size_t i = ((size_t)bid * 256 + tid) * 8;
    float4 a0 = *(const float4*)&A[i];
    float4 a1 = *(const float4*)&A[i + 4];
    float av[8] = {a0.x, a0.y, a0.z, a0.w, a1.x, a1.y, a1.z, a1.w};
    unsigned short h[8], l[8];
    #pragma unroll
    for (int j = 0; j < 8; ++j) split_hl(av[j], h[j], l[j]);
    *(uint4*)&aout[AHI_OFF + i] = *(uint4*)h;
    *(uint4*)&aout[ALO_OFF + i] = *(uint4*)l;
    return;
  }
  bid -= 4096;
  const int n0 = (bid % (N3H / 64)) * 64;
  const int k0 = (bid / (N3H / 64)) * 64;
  #pragma unroll
  for (int r = 0; r < 4; ++r) {
    int k = r * 16 + (tid >> 4);
    int n = (tid & 15) * 4;
    float4 v = *(const float4*)&W[(size_t)(k0 + k) * N3H + n0 + n];
    T[k][n + 0] = v.x; T[k][n + 1] = v.y; T[k][n + 2] = v.z; T[k][n + 3] = v.w;
  }
  __syncthreads();
  int n = tid >> 2;
  int kl = (tid & 3) * 16;
  unsigned short h[16], l[16];
  #pragma unroll
  for (int i = 0; i < 16; ++i) split_hl(T[kl + i][n], h[i], l[i]);
  size_t base = (size_t)(n0 + n) * 1024 + k0 + kl;
  *(uint4*)&ws[WH_OFF + base]     = *(uint4*)&h[0];
  *(uint4*)&ws[WH_OFF + base + 8] = *(uint4*)&h[8];
  *(uint4*)&ws[WL_OFF + base]     = *(uint4*)&l[0];
  *(uint4*)&ws[WL_OFF + base + 8] = *(uint4*)&l[8];
}

// ---------- MFMA QKV GEMM, 8-phase counted-vmcnt schedule ----------
// Virtual K = 3072 over the 3-term split:
//   t in [0,16):  Ah * Wh      t in [16,32): Al * Wh      t in [32,48): Ah * Wl
// BM=256, BN=192 (= one head's q|k|v), BK=64, 8 waves, dbuf LDS (112 KB), 1 block/CU.
// Grid = 32*16 = 512 blocks = exactly 2 full rounds on 256 CUs.
// LDS XOR-swizzle (row&7)<<4 applied on ds_read side; inverse pre-applied to the
// per-lane *global* source column (global_load_lds dest must stay linear).
__global__ __launch_bounds__(512, 2) void qkv_mfma(
    const unsigned short* __restrict__ ao,
    const unsigned short* __restrict__ ws,
    const float* __restrict__ bias,
    unsigned short* __restrict__ wso)
{
  __shared__ __align__(16) unsigned short sA[2][256 * 64];
  __shared__ __align__(16) unsigned short sB[2][192 * 64];

  const int tid  = threadIdx.x;
  const int wave = tid >> 6;
  const int lane = tid & 63;
  const int l16  = lane & 15;
  const int quad = lane >> 4;

  // XCD-aware swizzle (512 % 8 == 0 -> simple form is bijective)
  const int bid = blockIdx.x;
  const int swz = (bid & 7) * 64 + (bid >> 3);
  const int bn = swz >> 5;        // 0..15
  const int bm = swz & 31;        // 0..31
  const int n0 = bn * 192;
  const int m0 = bm * 256;

  const int wr = wave >> 2;       // 0..1
  const int wc = wave & 3;        // 0..3
  const int wm = wr * 128;
  const int wn = wc * 48;

  const unsigned short* AH = ao + AHI_OFF;
  const unsigned short* AL = ao + ALO_OFF;
  const unsigned short* WH = ws + WH_OFF;
  const unsigned short* WL = ws + WL_OFF;

  // staging geometry: each global_load_lds instr stages 64 rows x 16B (1KB/wave)
  const int rsub  = wave * 8 + (lane >> 3);          // row within 64-row group
  const int colsw = ((lane & 7) ^ (lane >> 3)) * 8;  // pre-swizzled source col (elems)
  const int rdswz = (l16 & 7) << 3;                  // read-side XOR (elems)

  f32x4 acc[8][3];
  #pragma unroll
  for (int i = 0; i < 8; ++i)
    #pragma unroll
    for (int j = 0; j < 3; ++j) acc[i][j] = (f32x4){0.f, 0.f, 0.f, 0.f};

  bf16x8 af[4], bf[3];

#define STAGE_A(tt, buf) do { \
    const unsigned short* _ab = ((tt) < 16 || (tt) >= 32) ? AH : AL; \
    const int _ko = ((tt) & 15) * 64; \
    _Pragma("unroll") \
    for (int q = 0; q < 4; ++q) \
      async16(&sA[buf][q * 4096 + wave * 512], \
              &_ab[(size_t)(m0 + q * 64 + rsub) * 1024 + _ko + colsw]); \
  } while (0)

#define STAGE_B(tt, buf) do { \
    const unsigned short* _wb = ((tt) < 32) ? WH : WL; \
    const int _ko = ((tt) & 15) * 64; \
    _Pragma("unroll") \
    for (int q = 0; q < 3; ++q) \
      async16(&sB[buf][q * 4096 + wave * 512], \
              &_wb[(size_t)(n0 + q * 64 + rsub) * 1024 + _ko + colsw]); \
  } while (0)

#define READ_A(h, kk) do { \
    _Pragma("unroll") \
    for (int i = 0; i < 4; ++i) { \
      int row = wm + ((h) * 4 + i) * 16 + l16; \
      af[i] = *(const bf16x8*)&sA[cur][row * 64 + ((((kk) * 32) + quad * 8) ^ rdswz)]; \
    } \
  } while (0)

#define READ_B(kk) do { \
    _Pragma("unroll") \
    for (int j = 0; j < 3; ++j) { \
      int row = wn + j * 16 + l16; \
      bf[j] = *(const bf16x8*)&sB[cur][row * 64 + ((((kk) * 32) + quad * 8) ^ rdswz)]; \
    } \
  } while (0)

#define MFMA12(h) do { \
    __builtin_amdgcn_s_setprio(1); \
    _Pragma("unroll") \
    for (int i = 0; i < 4; ++i) \
      _Pragma("unroll") \
      for (int j = 0; j < 3; ++j) \
        acc[(h) * 4 + i][j] = __builtin_amdgcn_mfma_f32_16x16x32_bf16( \
            af[i], bf[j], acc[(h) * 4 + i][j], 0, 0, 0); \
    __builtin_amdgcn_s_setprio(0); \
  } while (0)

#define BAR    __builtin_amdgcn_s_barrier()
#define SCHEDB __builtin_amdgcn_sched_barrier(0)
#define VMW0   asm volatile("s_waitcnt vmcnt(0)" ::: "memory")

  // 4 phases / tile; stage loads for t+1 issued in phases 0-1 (~2.5 phases of slack);
  // single vmcnt wait per tile, placed after phase-3 MFMA.
#define TILE_BODY(P, t_) do { \
    const int cur = (P); \
    /* phase 0 */ \
    READ_A(0, 0); READ_B(0); \
    if ((t_) + 1 < 48) STAGE_A((t_) + 1, 1 - (P)); \
    BAR; SCHEDB; MFMA12(0); BAR; \
    /* phase 1 */ \
    READ_A(1, 0); \
    if ((t_) + 1 < 48) STAGE_B((t_) + 1, 1 - (P)); \
    BAR; SCHEDB; MFMA12(1); BAR; \
    /* phase 2 */ \
    READ_A(0, 1); READ_B(1); \
    BAR; SCHEDB; MFMA12(0); BAR; \
    /* phase 3 */ \
    READ_A(1, 1); \
    BAR; SCHEDB; MFMA12(1); \
    VMW0; \
    BAR; \
  } while (0)

  // prologue: stage tile 0, drain, sync
  STAGE_A(0, 0); STAGE_B(0, 0);
  VMW0;
  BAR;

  for (int t = 0; t < 48; t += 2) {
    TILE_BODY(0, t);
    TILE_BODY(1, t + 1);
  }

  // ---------------- epilogue: bias + scatter to Q/K/V layouts ----------------
  const int bb   = m0 >> 10;
  const int bh   = bb * NHd + bn;          // n0/192 == bn == head
  const int srow = (m0 & 1023) + wm;       // multiple of 128

  #pragma unroll
  for (int j = 0; j < 3; ++j) {
    const int colb  = wn + j * 16;         // 0..176, 16-aligned, within one 64-group
    const int which = colb >> 6;
    const int d0    = colb & 63;
    const float bsj = bias[n0 + colb + l16];

    if (which == 0) {
      unsigned short* dst = wso + Q_OFF + ((size_t)bh * Sdim) * 128;
      #pragma unroll
      for (int i = 0; i < 8; ++i)
        #pragma unroll
        for (int r = 0; r < 4; ++r) {
          int s = srow + i * 16 + quad * 4 + r;
          unsigned short h, l;
          split_hl(acc[i][j][r] + bsj, h, l);
          dst[(size_t)s * 128 + d0 + l16]      = h;
          dst[(size_t)s * 128 + 64 + d0 + l16] = l;
        }
    } else if (which == 1) {
      const int c = d0 + l16;
      #pragma unroll
      for (int i = 0; i < 8; ++i) {
        int tile = (srow + i * 16) >> 6;
        int spb  = (i * 16 + quad * 4) & 63;
        unsigned short* dst = wso + K_OFF + (size_t)bh * 131072 + (size_t)tile * 8192;
        #pragma unroll
        for (int r = 0; r < 4; ++r) {
          int sp = spb + r;
          int idx = ((((sp >> 4) * 4 + (c >> 5)) * 64 + ((c >> 3) & 3) * 16 + (sp & 15)) << 3) + (c & 7);
          unsigned short h, l;
          split_hl(acc[i][j][r] + bsj, h, l);
          dst[idx]        = h;
          dst[idx + 1024] = l;
        }
      }
    } else {
      const int dr = d0 + l16;
      #pragma unroll
      for (int i = 0; i < 8; ++i) {
        int tile = (srow + i * 16) >> 6;
        int ky   = (i * 16 + quad * 4) & 63;
        unsigned short* dst = wso + V_OFF + (size_t)bh * 65536 + (size_t)tile * 4096;
        int idx = ((((dr >> 4) * 2 + (ky >> 5)) * 64 + ((ky >> 3) & 3) * 16 + (dr & 15)) << 3) + (ky & 7);
        unsigned short p[4];
        #pragma unroll
        for (int r = 0; r < 4; ++r) p[r] = f2bf(acc[i][j][r] + bsj);
        *(uint2*)&dst[idx] = *(uint2*)p;
      }
    }
  }

#undef STAGE_A
#undef STAGE_B
#undef READ_A
#undef READ_B
#undef MFMA12
#undef BAR
#undef SCHEDB
#undef VMW0
#undef TILE_BODY
}

// -------- MFMA flash attention: 64 q/block, single-buffer async staging, 4 blk/CU --------
__global__ __launch_bounds__(256, 4) void attn_mfma(
    const unsigned short* __restrict__ qhl,
    const unsigned short* __restrict__ khl,   // fragment-ordered tiles
    const unsigned short* __restrict__ vt,    // fragment-ordered tiles
    const int* __restrict__ mask,
    float* __restrict__ out)
{
  __shared__ unsigned short Ks[8192];
  __shared__ unsigned short Vs[4096];
  __shared__ unsigned short Pw[4][1024];
  __shared__ float msks[1024];

  const int tid  = threadIdx.x;
  const int wave = tid >> 6;
  const int lane = tid & 63;
  const int l16  = lane & 15;
  const int quad = lane >> 4;

  // bh fastest (stride 128 ≡ 0 mod 8) -> all q-tiles of one bh on the same XCD
  const int bh = blockIdx.x & 127;
  const int qt = blockIdx.x >> 7;
  const int bb = bh >> 4;
  const int q0 = qt * 64;

  const unsigned short* kplane = khl + (size_t)bh * 131072;
  const unsigned short* vplane = vt  + (size_t)bh * 65536;

  // mask row preload (once)
  {
    int4 mv = *(const int4*)&mask[bb * Sdim + tid * 4];
    msks[tid * 4 + 0] = mv.x ? 1.f : 0.f;
    msks[tid * 4 + 1] = mv.y ? 1.f : 0.f;
    msks[tid * 4 + 2] = mv.z ? 1.f : 0.f;
    msks[tid * 4 + 3] = mv.w ? 1.f : 0.f;
  }

  // Q fragments direct from global
  bf16x8 qf[4];
  {
    int row = q0 + wave * 16 + l16;
    const unsigned short* src = qhl + ((size_t)bh * Sdim + row) * 128;
    #pragma unroll
    for (int kk = 0; kk < 4; ++kk)
      qf[kk] = *(const bf16x8*)&src[kk * 32 + quad * 8];
  }

  f32x4 O[4] = {{0.f,0.f,0.f,0.f},{0.f,0.f,0.f,0.f},{0.f,0.f,0.f,0.f},{0.f,0.f,0.f,0.f}};
  float mrow[4] = {-INFINITY, -INFINITY, -INFINITY, -INFINITY};
  float lrow[4] = {0.f, 0.f, 0.f, 0.f};

  #pragma unroll 1
  for (int kt = 0; kt < 16; ++kt) {
    __syncthreads();   // previous tile's readers done (also orders msks on kt=0)
    {
      const unsigned short* ksrc = kplane + (size_t)kt * 8192;
      const unsigned short* vsrc = vplane + (size_t)kt * 4096;
      #pragma unroll
      for (int r = 0; r < 4; ++r)
        async16(&Ks[(r * 256 + tid) * 8], &ksrc[(size_t)(r * 256 + tid) * 8]);
      #pragma unroll
      for (int r = 0; r < 2; ++r)
        async16(&Vs[(r * 256 + tid) * 8], &vsrc[(size_t)(r * 256 + tid) * 8]);
    }
    __syncthreads();   // staged tile visible (drains vmcnt)

    // QK^T: 3-term split (hi·hi + lo·hi + hi·lo); conflict-free lane-contiguous reads
    f32x4 sc[4];
    #pragma unroll
    for (int ns = 0; ns < 4; ++ns) {
      f32x4 c = {0.f, 0.f, 0.f, 0.f};
      bf16x8 kf0 = *(const bf16x8*)&Ks[((ns * 4 + 0) * 64 + lane) * 8];
      bf16x8 kf1 = *(const bf16x8*)&Ks[((ns * 4 + 1) * 64 + lane) * 8];
      bf16x8 kf2 = *(const bf16x8*)&Ks[((ns * 4 + 2) * 64 + lane) * 8];
      bf16x8 kf3 = *(const bf16x8*)&Ks[((ns * 4 + 3) * 64 + lane) * 8];
      c = __builtin_amdgcn_mfma_f32_16x16x32_bf16(qf[0], kf0, c, 0, 0, 0);
      c = __builtin_amdgcn_mfma_f32_16x16x32_bf16(qf[1], kf1, c, 0, 0, 0);
      c = __builtin_amdgcn_mfma_f32_16x16x32_bf16(qf[2], kf0, c, 0, 0, 0);
      c = __builtin_amdgcn_mfma_f32_16x16x32_bf16(qf[3], kf1, c, 0, 0, 0);
      c = __builtin_amdgcn_mfma_f32_16x16x32_bf16(qf[0], kf2, c, 0, 0, 0);
      c = __builtin_amdgcn_mfma_f32_16x16x32_bf16(qf[1], kf3, c, 0, 0, 0);
      sc[ns] = c;
    }

    // mask + scale, row max
    float rmax[4] = {-INFINITY, -INFINITY, -INFINITY, -INFINITY};
    #pragma unroll
    for (int ns = 0; ns < 4; ++ns) {
      float mk = msks[kt * 64 + ns * 16 + l16];
      #pragma unroll
      for (int r = 0; r < 4; ++r) {
        float s = (mk != 0.f) ? -10000.f : sc[ns][r] * 8.f;
        sc[ns][r] = s;
        rmax[r] = fmaxf(rmax[r], s);
      }
    }
    #pragma unroll
    for (int r = 0; r < 4; ++r) {
      float v = rmax[r];
      v = fmaxf(v, __shfl_xor(v, 1, 16));
      v = fmaxf(v, __shfl_xor(v, 2, 16));
      v = fmaxf(v, __shfl_xor(v, 4, 16));
      v = fmaxf(v, __shfl_xor(v, 8, 16));
      rmax[r] = v;
    }

    float alpha[4];
    #pragma unroll
    for (int r = 0; r < 4; ++r) {
      float mn = fmaxf(mrow[r], rmax[r]);
      alpha[r] = __expf(mrow[r] - mn);
      mrow[r] = mn;
      lrow[r] *= alpha[r];
    }
    #pragma unroll
    for (int d = 0; d < 4; ++d)
      #pragma unroll
      for (int r = 0; r < 4; ++r) O[d][r] *= alpha[r];

    // exp, row-sum, write P (bf16) to per-wave LDS in A-fragment order
    float rsum[4] = {0.f, 0.f, 0.f, 0.f};
    #pragma unroll
    for (int ns = 0; ns < 4; ++ns) {
      int key = ns * 16 + l16;
      int cbase = (((key >> 5) * 4 + ((key >> 3) & 3)) * 16 + quad * 4) * 8 + (key & 7);
      #pragma unroll
      for (int r = 0; r < 4; ++r) {
        float p = __expf(sc[ns][r] - mrow[r]);
        rsum[r] += p;
        Pw[wave][cbase + r * 8] = f2bf(p);
      }
    }
    #pragma unroll
    for (int r = 0; r < 4; ++r) {
      float v = rsum[r];
      v += __shfl_xor(v, 1, 16);
      v += __shfl_xor(v, 2, 16);
      v += __shfl_xor(v, 4, 16);
      v += __shfl_xor(v, 8, 16);
      lrow[r] += v;
    }

    // P·V (wave-local; lane-contiguous reads)
    bf16x8 pf[2];
    #pragma unroll
    for (int kk = 0; kk < 2; ++kk)
      pf[kk] = *(const bf16x8*)&Pw[wave][((kk * 4 + quad) * 16 + l16) * 8];
    #pragma unroll
    for (int d = 0; d < 4; ++d)
      #pragma unroll
      for (int kk = 0; kk < 2; ++kk) {
        bf16x8 vf = *(const bf16x8*)&Vs[((d * 2 + kk) * 64 + lane) * 8];
        O[d] = __builtin_amdgcn_mfma_f32_16x16x32_bf16(pf[kk], vf, O[d], 0, 0, 0);
      }
  }

  // epilogue
  const int h = bh & 15;
  #pragma unroll
  for (int r = 0; r < 4; ++r) {
    float inv = 1.f / lrow[r];
    int q = q0 + wave * 16 + quad * 4 + r;
    float* dst = out + ((size_t)bb * Sdim + q) * Hdim + h * HDd;
    #pragma unroll
    for (int d = 0; d < 4; ++d)
      dst[d * 16 + l16] = O[d][r] * inv;
  }
}

extern "C" void kernel_launch(void* const* d_in, const int* in_sizes, int n_in,
                              void* d_out, int out_size, void* d_ws, size_t ws_size,
                              hipStream_t stream) {
  const float* hs   = (const float*)d_in[0];
  const int*   mask = (const int*)d_in[1];
  const float* w    = (const float*)d_in[2];
  const float* bias = (const float*)d_in[3];
  float* out = (float*)d_out;
  unsigned short* ws = (unsigned short*)d_ws;
  unsigned short* ao = (unsigned short*)d_out;   // A hi/lo scratch, overwritten by attn

  convert_AW<<<4096 + (N3H / 64) * (1024 / 64), 256, 0, stream>>>(hs, w, ao, ws);

  qkv_mfma<<<dim3(512), 512, 0, stream>>>(ao, ws, bias, ws);

  attn_mfma<<<Bdim * NHd * (Sdim / 64), 256, 0, stream>>>(
      ws + Q_OFF, ws + K_OFF, ws + V_OFF, mask, out);
}

// Round 2
// 376.667 us; speedup vs baseline: 1.1306x; 1.1306x over previous
//
#include <hip/hip_runtime.h>
#include <math.h>

#define Bdim 8
#define Sdim 1024
#define Hdim 1024
#define NHd 16
#define HDd 64
#define N3H 3072

// ws layout (ushort elements)
// Q: [bh][s][128] row-major (hi|lo). K: [bh][16 tiles][8192] fragment-ordered.
// V: [bh][16 tiles][4096] fragment-ordered. W^T hi/lo planes after.
#define Q_OFF   0u
#define K_OFF   16777216u
#define V_OFF   33554432u
#define WH_OFF  41943040u
#define WL_OFF  45088768u
// d_out scratch layout (ushort elements): Ahi, Alo
#define AHI_OFF 0u
#define ALO_OFF 8388608u

typedef __bf16 bf16x8 __attribute__((ext_vector_type(8)));
typedef float  f32x4  __attribute__((ext_vector_type(4)));

__device__ __forceinline__ unsigned short f2bf(float x) {
  unsigned b = __builtin_bit_cast(unsigned, x);
  return (unsigned short)((b + 0x7FFFu + ((b >> 16) & 1u)) >> 16);
}
__device__ __forceinline__ float bf2f(unsigned short h) {
  unsigned b = ((unsigned)h) << 16;
  return __builtin_bit_cast(float, b);
}
__device__ __forceinline__ void split_hl(float v, unsigned short& h, unsigned short& l) {
  h = f2bf(v);
  l = f2bf(v - bf2f(h));
}
__device__ __forceinline__ void async16(void* lds, const void* g) {
  __builtin_amdgcn_global_load_lds((const __attribute__((address_space(1))) unsigned int*)g,
                                   (__attribute__((address_space(3))) unsigned int*)lds, 16, 0, 0);
}

// ---------- fused convert: A -> hi/lo planes (d_out scratch); W -> W^T hi/lo (ws) ----------
__global__ __launch_bounds__(256) void convert_AW(
    const float* __restrict__ A, const float* __restrict__ W,
    unsigned short* __restrict__ aout, unsigned short* __restrict__ ws)
{
  __shared__ float T[64][65];
  const int tid = threadIdx.x;
  int bid = blockIdx.x;
  if (bid < 4096) {
    size_t i = ((size_t)bid * 256 + tid) * 8;
    float4 a0 = *(const float4*)&A[i];
    float4 a1 = *(const float4*)&A[i + 4];
    float av[8] = {a0.x, a0.y, a0.z, a0.w, a1.x, a1.y, a1.z, a1.w};
    unsigned short h[8], l[8];
    #pragma unroll
    for (int j = 0; j < 8; ++j) split_hl(av[j], h[j], l[j]);
    *(uint4*)&aout[AHI_OFF + i] = *(uint4*)h;
    *(uint4*)&aout[ALO_OFF + i] = *(uint4*)l;
    return;
  }
  bid -= 4096;
  const int n0 = (bid % (N3H / 64)) * 64;
  const int k0 = (bid / (N3H / 64)) * 64;
  #pragma unroll
  for (int r = 0; r < 4; ++r) {
    int k = r * 16 + (tid >> 4);
    int n = (tid & 15) * 4;
    float4 v = *(const float4*)&W[(size_t)(k0 + k) * N3H + n0 + n];
    T[k][n + 0] = v.x; T[k][n + 1] = v.y; T[k][n + 2] = v.z; T[k][n + 3] = v.w;
  }
  __syncthreads();
  int n = tid >> 2;
  int kl = (tid & 3) * 16;
  unsigned short h[16], l[16];
  #pragma unroll
  for (int i = 0; i < 16; ++i) split_hl(T[kl + i][n], h[i], l[i]);
  size_t base = (size_t)(n0 + n) * 1024 + k0 + kl;
  *(uint4*)&ws[WH_OFF + base]     = *(uint4*)&h[0];
  *(uint4*)&ws[WH_OFF + base + 8] = *(uint4*)&h[8];
  *(uint4*)&ws[WL_OFF + base]     = *(uint4*)&l[0];
  *(uint4*)&ws[WL_OFF + base + 8] = *(uint4*)&l[8];
}

// ---------- MFMA QKV GEMM, 8-phase COUNTED-vmcnt schedule (T3+T4+T2+T5+T1) ----------
// Virtual K = 3072 over the 3-term split:
//   t in [0,16):  Ah * Wh      t in [16,32): Al * Wh      t in [32,48): Ah * Wl
// BM=256, BN=192 (= one head's q|k|v), BK=64, 8 waves, dbuf LDS (112 KB), 1 block/CU.
// Pipeline: B(t+1) staged at ph0 of tile t; A(t+2) staged at tile-t end (after the
// post-MFMA barrier, so all reads of buf P are serviced); boundary wait is
// s_waitcnt vmcnt(4) (4 newest = t+2's A-loads; all of t+1 older => complete) + barrier.
// Steady state NEVER drains vmcnt to 0 (single vmcnt(0) at t=46).
// XCD mapping: each XCD owns an 8bm x 8bn region; its 32 concurrent blocks form an
// 8bm x 4bn rectangle -> A shared 4-way, W shared 8-way within the XCD's L2.
__global__ __launch_bounds__(512, 2) void qkv_mfma(
    const unsigned short* __restrict__ ao,
    const unsigned short* __restrict__ ws,
    const float* __restrict__ bias,
    unsigned short* __restrict__ wso)
{
  __shared__ __align__(16) unsigned short sA[2][256 * 64];
  __shared__ __align__(16) unsigned short sB[2][192 * 64];

  const int tid  = threadIdx.x;
  const int wave = tid >> 6;
  const int lane = tid & 63;
  const int l16  = lane & 15;
  const int quad = lane >> 4;

  // rectangular XCD-region mapping (bijective: 512 = 8 XCD * 64)
  const int bid = blockIdx.x;
  const int xcd = bid & 7;
  const int idx = bid >> 3;                                  // 0..63
  const int bm = ((xcd >> 1) << 3) | (idx & 7);              // 0..31
  const int bn = ((xcd & 1) << 3) | (((idx >> 5) << 2) | ((idx >> 3) & 3)); // 0..15
  const int n0 = bn * 192;
  const int m0 = bm * 256;

  const int wr = wave >> 2;       // 0..1
  const int wc = wave & 3;        // 0..3
  const int wm = wr * 128;
  const int wn = wc * 48;

  const unsigned short* AH = ao + AHI_OFF;
  const unsigned short* AL = ao + ALO_OFF;
  const unsigned short* WH = ws + WH_OFF;
  const unsigned short* WL = ws + WL_OFF;

  // staging geometry: each global_load_lds instr stages 64 rows x 16B (1KB/wave)
  const int rsub  = wave * 8 + (lane >> 3);          // row within 64-row group
  const int colsw = ((lane & 7) ^ (lane >> 3)) * 8;  // pre-swizzled source col (elems)
  const int rdswz = (l16 & 7) << 3;                  // read-side XOR (elems)

  f32x4 acc[8][3];
  #pragma unroll
  for (int i = 0; i < 8; ++i)
    #pragma unroll
    for (int j = 0; j < 3; ++j) acc[i][j] = (f32x4){0.f, 0.f, 0.f, 0.f};

  bf16x8 af[4], bf[3];

#define STAGE_A(tt, buf) do { \
    const unsigned short* _ab = ((tt) < 16 || (tt) >= 32) ? AH : AL; \
    const int _ko = ((tt) & 15) * 64; \
    _Pragma("unroll") \
    for (int q = 0; q < 4; ++q) \
      async16(&sA[buf][q * 4096 + wave * 512], \
              &_ab[(size_t)(m0 + q * 64 + rsub) * 1024 + _ko + colsw]); \
  } while (0)

#define STAGE_B(tt, buf) do { \
    const unsigned short* _wb = ((tt) < 32) ? WH : WL; \
    const int _ko = ((tt) & 15) * 64; \
    _Pragma("unroll") \
    for (int q = 0; q < 3; ++q) \
      async16(&sB[buf][q * 4096 + wave * 512], \
              &_wb[(size_t)(n0 + q * 64 + rsub) * 1024 + _ko + colsw]); \
  } while (0)

#define READ_A(h, kk) do { \
    _Pragma("unroll") \
    for (int i = 0; i < 4; ++i) { \
      int row = wm + ((h) * 4 + i) * 16 + l16; \
      af[i] = *(const bf16x8*)&sA[cur][row * 64 + ((((kk) * 32) + quad * 8) ^ rdswz)]; \
    } \
  } while (0)

#define READ_B(kk) do { \
    _Pragma("unroll") \
    for (int j = 0; j < 3; ++j) { \
      int row = wn + j * 16 + l16; \
      bf[j] = *(const bf16x8*)&sB[cur][row * 64 + ((((kk) * 32) + quad * 8) ^ rdswz)]; \
    } \
  } while (0)

#define MFMA12(h) do { \
    __builtin_amdgcn_s_setprio(1); \
    _Pragma("unroll") \
    for (int i = 0; i < 4; ++i) \
      _Pragma("unroll") \
      for (int j = 0; j < 3; ++j) \
        acc[(h) * 4 + i][j] = __builtin_amdgcn_mfma_f32_16x16x32_bf16( \
            af[i], bf[j], acc[(h) * 4 + i][j], 0, 0, 0); \
    __builtin_amdgcn_s_setprio(0); \
  } while (0)

#define BAR    __builtin_amdgcn_s_barrier()
#define SCHEDB __builtin_amdgcn_sched_barrier(0)
#define VMW4   asm volatile("s_waitcnt vmcnt(4)" ::: "memory")
#define VMW0   asm volatile("s_waitcnt vmcnt(0)" ::: "memory")

#define TILE_BODY(P, t_) do { \
    const int cur = (P); \
    /* phase 0 */ \
    READ_A(0, 0); READ_B(0); \
    if ((t_) + 1 < 48) STAGE_B((t_) + 1, 1 - (P)); \
    BAR; SCHEDB; MFMA12(0); BAR; \
    /* phase 1 */ \
    READ_A(1, 0); \
    BAR; SCHEDB; MFMA12(1); BAR; \
    /* phase 2 */ \
    READ_A(0, 1); READ_B(1); \
    BAR; SCHEDB; MFMA12(0); BAR; \
    /* phase 3 */ \
    READ_A(1, 1); \
    BAR; SCHEDB; MFMA12(1); BAR; \
    /* tile boundary: stage A two tiles ahead, counted wait for t+1 */ \
    if ((t_) + 2 < 48) STAGE_A((t_) + 2, (P)); \
    if ((t_) + 1 < 48) { \
      if ((t_) + 2 < 48) { VMW4; } else { VMW0; } \
      BAR; \
    } \
  } while (0)

  // prologue: stage tile 0 fully + tile 1's A; counted wait leaves t1's A in flight
  STAGE_A(0, 0); STAGE_B(0, 0);
  STAGE_A(1, 1);
  VMW4;
  BAR;

  for (int t = 0; t < 48; t += 2) {
    TILE_BODY(0, t);
    TILE_BODY(1, t + 1);
  }

  // ---------------- epilogue: bias + scatter to Q/K/V layouts ----------------
  const int bb   = m0 >> 10;
  const int bh   = bb * NHd + bn;          // n0/192 == bn == head
  const int srow = (m0 & 1023) + wm;       // multiple of 128

  #pragma unroll
  for (int j = 0; j < 3; ++j) {
    const int colb  = wn + j * 16;         // 0..176, 16-aligned, within one 64-group
    const int which = colb >> 6;
    const int d0    = colb & 63;
    const float bsj = bias[n0 + colb + l16];

    if (which == 0) {
      unsigned short* dst = wso + Q_OFF + ((size_t)bh * Sdim) * 128;
      #pragma unroll
      for (int i = 0; i < 8; ++i)
        #pragma unroll
        for (int r = 0; r < 4; ++r) {
          int s = srow + i * 16 + quad * 4 + r;
          unsigned short h, l;
          split_hl(acc[i][j][r] + bsj, h, l);
          dst[(size_t)s * 128 + d0 + l16]      = h;
          dst[(size_t)s * 128 + 64 + d0 + l16] = l;
        }
    } else if (which == 1) {
      const int c = d0 + l16;
      #pragma unroll
      for (int i = 0; i < 8; ++i) {
        int tile = (srow + i * 16) >> 6;
        int spb  = (i * 16 + quad * 4) & 63;
        unsigned short* dst = wso + K_OFF + (size_t)bh * 131072 + (size_t)tile * 8192;
        #pragma unroll
        for (int r = 0; r < 4; ++r) {
          int sp = spb + r;
          int idx = ((((sp >> 4) * 4 + (c >> 5)) * 64 + ((c >> 3) & 3) * 16 + (sp & 15)) << 3) + (c & 7);
          unsigned short h, l;
          split_hl(acc[i][j][r] + bsj, h, l);
          dst[idx]        = h;
          dst[idx + 1024] = l;
        }
      }
    } else {
      const int dr = d0 + l16;
      #pragma unroll
      for (int i = 0; i < 8; ++i) {
        int tile = (srow + i * 16) >> 6;
        int ky   = (i * 16 + quad * 4) & 63;
        unsigned short* dst = wso + V_OFF + (size_t)bh * 65536 + (size_t)tile * 4096;
        int idx = ((((dr >> 4) * 2 + (ky >> 5)) * 64 + ((ky >> 3) & 3) * 16 + (dr & 15)) << 3) + (ky & 7);
        unsigned short p[4];
        #pragma unroll
        for (int r = 0; r < 4; ++r) p[r] = f2bf(acc[i][j][r] + bsj);
        *(uint2*)&dst[idx] = *(uint2*)p;
      }
    }
  }

#undef STAGE_A
#undef STAGE_B
#undef READ_A
#undef READ_B
#undef MFMA12
#undef BAR
#undef SCHEDB
#undef VMW4
#undef VMW0
#undef TILE_BODY
}

// -------- MFMA flash attention: 64 q/block, single-buffer async staging, 4 blk/CU --------
__global__ __launch_bounds__(256, 4) void attn_mfma(
    const unsigned short* __restrict__ qhl,
    const unsigned short* __restrict__ khl,   // fragment-ordered tiles
    const unsigned short* __restrict__ vt,    // fragment-ordered tiles
    const int* __restrict__ mask,
    float* __restrict__ out)
{
  __shared__ unsigned short Ks[8192];
  __shared__ unsigned short Vs[4096];
  __shared__ unsigned short Pw[4][1024];
  __shared__ float msks[1024];

  const int tid  = threadIdx.x;
  const int wave = tid >> 6;
  const int lane = tid & 63;
  const int l16  = lane & 15;
  const int quad = lane >> 4;

  // bh fastest (stride 128 ≡ 0 mod 8) -> all q-tiles of one bh on the same XCD
  const int bh = blockIdx.x & 127;
  const int qt = blockIdx.x >> 7;
  const int bb = bh >> 4;
  const int q0 = qt * 64;

  const unsigned short* kplane = khl + (size_t)bh * 131072;
  const unsigned short* vplane = vt  + (size_t)bh * 65536;

  // mask row preload (once)
  {
    int4 mv = *(const int4*)&mask[bb * Sdim + tid * 4];
    msks[tid * 4 + 0] = mv.x ? 1.f : 0.f;
    msks[tid * 4 + 1] = mv.y ? 1.f : 0.f;
    msks[tid * 4 + 2] = mv.z ? 1.f : 0.f;
    msks[tid * 4 + 3] = mv.w ? 1.f : 0.f;
  }

  // Q fragments direct from global
  bf16x8 qf[4];
  {
    int row = q0 + wave * 16 + l16;
    const unsigned short* src = qhl + ((size_t)bh * Sdim + row) * 128;
    #pragma unroll
    for (int kk = 0; kk < 4; ++kk)
      qf[kk] = *(const bf16x8*)&src[kk * 32 + quad * 8];
  }

  f32x4 O[4] = {{0.f,0.f,0.f,0.f},{0.f,0.f,0.f,0.f},{0.f,0.f,0.f,0.f},{0.f,0.f,0.f,0.f}};
  float mrow[4] = {-INFINITY, -INFINITY, -INFINITY, -INFINITY};
  float lrow[4] = {0.f, 0.f, 0.f, 0.f};

  #pragma unroll 1
  for (int kt = 0; kt < 16; ++kt) {
    __syncthreads();   // previous tile's readers done (also orders msks on kt=0)
    {
      const unsigned short* ksrc = kplane + (size_t)kt * 8192;
      const unsigned short* vsrc = vplane + (size_t)kt * 4096;
      #pragma unroll
      for (int r = 0; r < 4; ++r)
        async16(&Ks[(r * 256 + tid) * 8], &ksrc[(size_t)(r * 256 + tid) * 8]);
      #pragma unroll
      for (int r = 0; r < 2; ++r)
        async16(&Vs[(r * 256 + tid) * 8], &vsrc[(size_t)(r * 256 + tid) * 8]);
    }
    __syncthreads();   // staged tile visible (drains vmcnt)

    // QK^T: 3-term split (hi·hi + lo·hi + hi·lo); conflict-free lane-contiguous reads
    f32x4 sc[4];
    #pragma unroll
    for (int ns = 0; ns < 4; ++ns) {
      f32x4 c = {0.f, 0.f, 0.f, 0.f};
      bf16x8 kf0 = *(const bf16x8*)&Ks[((ns * 4 + 0) * 64 + lane) * 8];
      bf16x8 kf1 = *(const bf16x8*)&Ks[((ns * 4 + 1) * 64 + lane) * 8];
      bf16x8 kf2 = *(const bf16x8*)&Ks[((ns * 4 + 2) * 64 + lane) * 8];
      bf16x8 kf3 = *(const bf16x8*)&Ks[((ns * 4 + 3) * 64 + lane) * 8];
      c = __builtin_amdgcn_mfma_f32_16x16x32_bf16(qf[0], kf0, c, 0, 0, 0);
      c = __builtin_amdgcn_mfma_f32_16x16x32_bf16(qf[1], kf1, c, 0, 0, 0);
      c = __builtin_amdgcn_mfma_f32_16x16x32_bf16(qf[2], kf0, c, 0, 0, 0);
      c = __builtin_amdgcn_mfma_f32_16x16x32_bf16(qf[3], kf1, c, 0, 0, 0);
      c = __builtin_amdgcn_mfma_f32_16x16x32_bf16(qf[0], kf2, c, 0, 0, 0);
      c = __builtin_amdgcn_mfma_f32_16x16x32_bf16(qf[1], kf3, c, 0, 0, 0);
      sc[ns] = c;
    }

    // mask + scale, row max
    float rmax[4] = {-INFINITY, -INFINITY, -INFINITY, -INFINITY};
    #pragma unroll
    for (int ns = 0; ns < 4; ++ns) {
      float mk = msks[kt * 64 + ns * 16 + l16];
      #pragma unroll
      for (int r = 0; r < 4; ++r) {
        float s = (mk != 0.f) ? -10000.f : sc[ns][r] * 8.f;
        sc[ns][r] = s;
        rmax[r] = fmaxf(rmax[r], s);
      }
    }
    #pragma unroll
    for (int r = 0; r < 4; ++r) {
      float v = rmax[r];
      v = fmaxf(v, __shfl_xor(v, 1, 16));
      v = fmaxf(v, __shfl_xor(v, 2, 16));
      v = fmaxf(v, __shfl_xor(v, 4, 16));
      v = fmaxf(v, __shfl_xor(v, 8, 16));
      rmax[r] = v;
    }

    float alpha[4];
    #pragma unroll
    for (int r = 0; r < 4; ++r) {
      float mn = fmaxf(mrow[r], rmax[r]);
      alpha[r] = __expf(mrow[r] - mn);
      mrow[r] = mn;
      lrow[r] *= alpha[r];
    }
    #pragma unroll
    for (int d = 0; d < 4; ++d)
      #pragma unroll
      for (int r = 0; r < 4; ++r) O[d][r] *= alpha[r];

    // exp, row-sum, write P (bf16) to per-wave LDS in A-fragment order
    float rsum[4] = {0.f, 0.f, 0.f, 0.f};
    #pragma unroll
    for (int ns = 0; ns < 4; ++ns) {
      int key = ns * 16 + l16;
      int cbase = (((key >> 5) * 4 + ((key >> 3) & 3)) * 16 + quad * 4) * 8 + (key & 7);
      #pragma unroll
      for (int r = 0; r < 4; ++r) {
        float p = __expf(sc[ns][r] - mrow[r]);
        rsum[r] += p;
        Pw[wave][cbase + r * 8] = f2bf(p);
      }
    }
    #pragma unroll
    for (int r = 0; r < 4; ++r) {
      float v = rsum[r];
      v += __shfl_xor(v, 1, 16);
      v += __shfl_xor(v, 2, 16);
      v += __shfl_xor(v, 4, 16);
      v += __shfl_xor(v, 8, 16);
      lrow[r] += v;
    }

    // P·V (wave-local; lane-contiguous reads)
    bf16x8 pf[2];
    #pragma unroll
    for (int kk = 0; kk < 2; ++kk)
      pf[kk] = *(const bf16x8*)&Pw[wave][((kk * 4 + quad) * 16 + l16) * 8];
    #pragma unroll
    for (int d = 0; d < 4; ++d)
      #pragma unroll
      for (int kk = 0; kk < 2; ++kk) {
        bf16x8 vf = *(const bf16x8*)&Vs[((d * 2 + kk) * 64 + lane) * 8];
        O[d] = __builtin_amdgcn_mfma_f32_16x16x32_bf16(pf[kk], vf, O[d], 0, 0, 0);
      }
  }

  // epilogue
  const int h = bh & 15;
  #pragma unroll
  for (int r = 0; r < 4; ++r) {
    float inv = 1.f / lrow[r];
    int q = q0 + wave * 16 + quad * 4 + r;
    float* dst = out + ((size_t)bb * Sdim + q) * Hdim + h * HDd;
    #pragma unroll
    for (int d = 0; d < 4; ++d)
      dst[d * 16 + l16] = O[d][r] * inv;
  }
}

extern "C" void kernel_launch(void* const* d_in, const int* in_sizes, int n_in,
                              void* d_out, int out_size, void* d_ws, size_t ws_size,
                              hipStream_t stream) {
  const float* hs   = (const float*)d_in[0];
  const int*   mask = (const int*)d_in[1];
  const float* w    = (const float*)d_in[2];
  const float* bias = (const float*)d_in[3];
  float* out = (float*)d_out;
  unsigned short* ws = (unsigned short*)d_ws;
  unsigned short* ao = (unsigned short*)d_out;   // A hi/lo scratch, overwritten by attn

  convert_AW<<<4096 + (N3H / 64) * (1024 / 64), 256, 0, stream>>>(hs, w, ao, ws);

  qkv_mfma<<<dim3(512), 512, 0, stream>>>(ao, ws, bias, ws);

  attn_mfma<<<Bdim * NHd * (Sdim / 64), 256, 0, stream>>>(
      ws + Q_OFF, ws + K_OFF, ws + V_OFF, mask, out);
}

// Round 3
// 375.743 us; speedup vs baseline: 1.1334x; 1.0025x over previous
//
#include <hip/hip_runtime.h>
#include <math.h>

#define Bdim 8
#define Sdim 1024
#define Hdim 1024
#define NHd 16
#define HDd 64
#define N3H 3072

// ws layout (ushort elements)
// Q: [bh][s][128] row-major (hi|lo). K: [bh][16 tiles][8192] fragment-ordered.
// V: [bh][16 tiles][4096] fragment-ordered. W^T hi/lo planes after.
#define Q_OFF   0u
#define K_OFF   16777216u
#define V_OFF   33554432u
#define WH_OFF  41943040u
#define WL_OFF  45088768u
// d_out scratch layout (ushort elements): Ahi, Alo
#define AHI_OFF 0u
#define ALO_OFF 8388608u

typedef __bf16 bf16x8 __attribute__((ext_vector_type(8)));
typedef float  f32x4  __attribute__((ext_vector_type(4)));
typedef float  f32x16 __attribute__((ext_vector_type(16)));

__device__ __forceinline__ unsigned short f2bf(float x) {
  unsigned b = __builtin_bit_cast(unsigned, x);
  return (unsigned short)((b + 0x7FFFu + ((b >> 16) & 1u)) >> 16);
}
__device__ __forceinline__ float bf2f(unsigned short h) {
  unsigned b = ((unsigned)h) << 16;
  return __builtin_bit_cast(float, b);
}
__device__ __forceinline__ void split_hl(float v, unsigned short& h, unsigned short& l) {
  h = f2bf(v);
  l = f2bf(v - bf2f(h));
}
__device__ __forceinline__ void async16(void* lds, const void* g) {
  __builtin_amdgcn_global_load_lds((const __attribute__((address_space(1))) unsigned int*)g,
                                   (__attribute__((address_space(3))) unsigned int*)lds, 16, 0, 0);
}

// ---------- fused convert: A -> hi/lo planes (d_out scratch); W -> W^T hi/lo (ws) ----------
__global__ __launch_bounds__(256) void convert_AW(
    const float* __restrict__ A, const float* __restrict__ W,
    unsigned short* __restrict__ aout, unsigned short* __restrict__ ws)
{
  __shared__ float T[64][65];
  const int tid = threadIdx.x;
  int bid = blockIdx.x;
  if (bid < 4096) {
    size_t i = ((size_t)bid * 256 + tid) * 8;
    float4 a0 = *(const float4*)&A[i];
    float4 a1 = *(const float4*)&A[i + 4];
    float av[8] = {a0.x, a0.y, a0.z, a0.w, a1.x, a1.y, a1.z, a1.w};
    unsigned short h[8], l[8];
    #pragma unroll
    for (int j = 0; j < 8; ++j) split_hl(av[j], h[j], l[j]);
    *(uint4*)&aout[AHI_OFF + i] = *(uint4*)h;
    *(uint4*)&aout[ALO_OFF + i] = *(uint4*)l;
    return;
  }
  bid -= 4096;
  const int n0 = (bid % (N3H / 64)) * 64;
  const int k0 = (bid / (N3H / 64)) * 64;
  #pragma unroll
  for (int r = 0; r < 4; ++r) {
    int k = r * 16 + (tid >> 4);
    int n = (tid & 15) * 4;
    float4 v = *(const float4*)&W[(size_t)(k0 + k) * N3H + n0 + n];
    T[k][n + 0] = v.x; T[k][n + 1] = v.y; T[k][n + 2] = v.z; T[k][n + 3] = v.w;
  }
  __syncthreads();
  int n = tid >> 2;
  int kl = (tid & 3) * 16;
  unsigned short h[16], l[16];
  #pragma unroll
  for (int i = 0; i < 16; ++i) split_hl(T[kl + i][n], h[i], l[i]);
  size_t base = (size_t)(n0 + n) * 1024 + k0 + kl;
  *(uint4*)&ws[WH_OFF + base]     = *(uint4*)&h[0];
  *(uint4*)&ws[WH_OFF + base + 8] = *(uint4*)&h[8];
  *(uint4*)&ws[WL_OFF + base]     = *(uint4*)&l[0];
  *(uint4*)&ws[WL_OFF + base + 8] = *(uint4*)&l[8];
}

// ---------- MFMA QKV GEMM: 32x32x16 shape, counted-vmcnt pipeline ----------
// Virtual K = 3072 over the 3-term split:
//   t in [0,16):  Ah * Wh      t in [16,32): Al * Wh      t in [32,48): Ah * Wl
// BM=256, BN=384 (= 2 heads), BK=64, 8 waves (2M x 4N), wave tile 128x96.
// LDS = (256+384)*64*2B * 2buf = 163840 B (exactly 160 KiB, AITER-proven size).
// Grid = 32 x 8 = 256 blocks = exactly 1 per CU, single round.
// 32x32x16 halves LDS-read bytes per FLOP vs 16x16x32 (the R2 bottleneck) and
// runs at 2495 vs 2075 TF ceiling.
// Pipeline (per wave, per tile): ph0/ph1 issue B(t+1) halves; boundary issues
// A(t+2); boundary wait = vmcnt(4) (only A(t+2) newer) -> never drains to 0.
// XCD mapping: each XCD owns an 8bm x 4bn rectangle -> A 4-way, W 8-way L2 share.
__global__ __launch_bounds__(512, 2) void qkv_mfma(
    const unsigned short* __restrict__ ao,
    const unsigned short* __restrict__ ws,
    const float* __restrict__ bias,
    unsigned short* __restrict__ wso)
{
  __shared__ __align__(16) unsigned short sA[2][256 * 64];
  __shared__ __align__(16) unsigned short sB[2][384 * 64];

  const int tid  = threadIdx.x;
  const int wave = tid >> 6;
  const int lane = tid & 63;
  const int l32  = lane & 31;
  const int hi   = lane >> 5;

  // rectangular XCD-region mapping (bijective: 256 = 8 XCD * 32)
  const int bid = blockIdx.x;
  const int xcd = bid & 7;
  const int g   = bid >> 3;                      // 0..31
  const int bm  = ((xcd >> 1) << 3) | (g & 7);   // 0..31
  const int bn  = ((xcd & 1) << 2) | (g >> 3);   // 0..7
  const int m0  = bm * 256;
  const int n0  = bn * 384;

  const int wm = (wave >> 2) * 128;   // 0,128
  const int wn = (wave & 3) * 96;     // 0,96,192,288

  const unsigned short* AH = ao + AHI_OFF;
  const unsigned short* AL = ao + ALO_OFF;
  const unsigned short* WH = ws + WH_OFF;
  const unsigned short* WL = ws + WL_OFF;

  // staging geometry: each async16 stages 8 rows x 64 elems (1KB per wave-instr)
  const int rsub  = wave * 8 + (lane >> 3);          // row within 64-row group
  const int colsw = ((lane & 7) ^ (lane >> 3)) * 8;  // pre-swizzled source col (elems)
  const int rdswz = (lane & 7) << 3;                 // read-side XOR (elems); row&7 == lane&7

  f32x16 acc[4][3];
  #pragma unroll
  for (int i = 0; i < 4; ++i)
    #pragma unroll
    for (int j = 0; j < 3; ++j)
      acc[i][j] = (f32x16){0.f,0.f,0.f,0.f,0.f,0.f,0.f,0.f,0.f,0.f,0.f,0.f,0.f,0.f,0.f,0.f};

  bf16x8 af[4], bf[3];

#define STAGE_A(tt, buf) do { \
    const unsigned short* _ab = ((tt) < 16 || (tt) >= 32) ? AH : AL; \
    const int _ko = ((tt) & 15) * 64; \
    _Pragma("unroll") \
    for (int q = 0; q < 4; ++q) \
      async16(&sA[buf][q * 4096 + wave * 512], \
              &_ab[(size_t)(m0 + q * 64 + rsub) * 1024 + _ko + colsw]); \
  } while (0)

#define STAGE_B_H(tt, buf, h_) do { \
    const unsigned short* _wb = ((tt) < 32) ? WH : WL; \
    const int _ko = ((tt) & 15) * 64; \
    _Pragma("unroll") \
    for (int q = (h_) * 3; q < (h_) * 3 + 3; ++q) \
      async16(&sB[buf][q * 4096 + wave * 512], \
              &_wb[(size_t)(n0 + q * 64 + rsub) * 1024 + _ko + colsw]); \
  } while (0)

#define READ_AB(s) do { \
    const int _c = (((s) * 16 + hi * 8) ^ rdswz); \
    _Pragma("unroll") \
    for (int i = 0; i < 4; ++i) \
      af[i] = *(const bf16x8*)&sA[cur][(wm + i * 32 + l32) * 64 + _c]; \
    _Pragma("unroll") \
    for (int j = 0; j < 3; ++j) \
      bf[j] = *(const bf16x8*)&sB[cur][(wn + j * 32 + l32) * 64 + _c]; \
  } while (0)

#define MFMA12 do { \
    __builtin_amdgcn_s_setprio(1); \
    _Pragma("unroll") \
    for (int i = 0; i < 4; ++i) \
      _Pragma("unroll") \
      for (int j = 0; j < 3; ++j) \
        acc[i][j] = __builtin_amdgcn_mfma_f32_32x32x16_bf16( \
            af[i], bf[j], acc[i][j], 0, 0, 0); \
    __builtin_amdgcn_s_setprio(0); \
  } while (0)

#define BAR    __builtin_amdgcn_s_barrier()
#define SCHEDB __builtin_amdgcn_sched_barrier(0)
#define VMW4   asm volatile("s_waitcnt vmcnt(4)" ::: "memory")
#define VMW0   asm volatile("s_waitcnt vmcnt(0)" ::: "memory")

#define TILE_BODY(P, t_) do { \
    const int cur = (P); \
    READ_AB(0); \
    if ((t_) + 1 < 48) STAGE_B_H((t_) + 1, 1 - (P), 0); \
    BAR; SCHEDB; MFMA12; BAR; \
    READ_AB(1); \
    if ((t_) + 1 < 48) STAGE_B_H((t_) + 1, 1 - (P), 1); \
    BAR; SCHEDB; MFMA12; BAR; \
    READ_AB(2); \
    BAR; SCHEDB; MFMA12; BAR; \
    READ_AB(3); \
    BAR; SCHEDB; MFMA12; BAR; \
    /* tile boundary: buf P reads all done (post-MFMA barrier) -> refill it */ \
    if ((t_) + 2 < 48) STAGE_A((t_) + 2, (P)); \
    if ((t_) + 1 < 48) { \
      if ((t_) + 2 < 48) { VMW4; } else { VMW0; } \
      BAR; \
    } \
  } while (0)

  // prologue: tile 0 fully + tile 1's A; counted wait leaves t1's A in flight
  STAGE_A(0, 0); STAGE_B_H(0, 0, 0); STAGE_B_H(0, 0, 1);
  STAGE_A(1, 1);
  VMW4;
  BAR;

  for (int t = 0; t < 48; t += 2) {
    TILE_BODY(0, t);
    TILE_BODY(1, t + 1);
  }

  // ---------------- epilogue: bias + scatter to Q/K/V layouts ----------------
  // 32x32 C layout: col = lane&31, row = (reg&3) + 8*(reg>>2) + 4*(lane>>5)
  const int bb   = m0 >> 10;
  const int srow = (m0 & 1023) + wm;       // 128-aligned

  #pragma unroll
  for (int j = 0; j < 3; ++j) {
    const int colb   = wn + j * 32;              // 0..352, 32-aligned
    const int head   = (bn << 1) + (colb >= 192 ? 1 : 0);
    const int within = (colb >= 192) ? colb - 192 : colb;
    const int which  = within >> 6;              // 0=Q 1=K 2=V
    const int dsub   = within & 63;              // 0 or 32
    const int bh     = bb * NHd + head;
    const float bsj  = bias[n0 + colb + l32];

    #pragma unroll
    for (int i = 0; i < 4; ++i) {
      const int sbase = srow + i * 32;           // 32-aligned, within [0,1024)
      const int tile  = sbase >> 6;
      const int kbase = sbase & 32;              // 0 or 32

      if (which == 0) {
        unsigned short* dst = wso + Q_OFF + ((size_t)bh * Sdim + sbase) * 128;
        const int d = dsub + l32;
        #pragma unroll
        for (int r = 0; r < 16; ++r) {
          int rl = (r & 3) + 8 * (r >> 2) + 4 * hi;
          unsigned short h_, l_;
          split_hl(acc[i][j][r] + bsj, h_, l_);
          dst[(size_t)rl * 128 + d]      = h_;
          dst[(size_t)rl * 128 + 64 + d] = l_;
        }
      } else if (which == 1) {
        const int c = dsub + l32;
        unsigned short* dst = wso + K_OFF + (size_t)bh * 131072 + (size_t)tile * 8192;
        #pragma unroll
        for (int r = 0; r < 16; ++r) {
          int sp = kbase + (r & 3) + 8 * (r >> 2) + 4 * hi;
          int idx = ((((sp >> 4) * 4 + (c >> 5)) * 64 + ((c >> 3) & 3) * 16 + (sp & 15)) << 3) + (c & 7);
          unsigned short h_, l_;
          split_hl(acc[i][j][r] + bsj, h_, l_);
          dst[idx]        = h_;
          dst[idx + 1024] = l_;
        }
      } else {
        const int dr = dsub + l32;
        unsigned short* dst = wso + V_OFF + (size_t)bh * 65536 + (size_t)tile * 4096;
        #pragma unroll
        for (int rg = 0; rg < 4; ++rg) {
          int ky0 = kbase + rg * 8 + 4 * hi;     // 4-aligned, 4 consecutive regs
          int idx = ((((dr >> 4) * 2 + (ky0 >> 5)) * 64 + ((ky0 >> 3) & 3) * 16 + (dr & 15)) << 3) + (ky0 & 7);
          unsigned short p[4];
          #pragma unroll
          for (int e = 0; e < 4; ++e) p[e] = f2bf(acc[i][j][rg * 4 + e] + bsj);
          *(uint2*)&dst[idx] = *(uint2*)p;
        }
      }
    }
  }

#undef STAGE_A
#undef STAGE_B_H
#undef READ_AB
#undef MFMA12
#undef BAR
#undef SCHEDB
#undef VMW4
#undef VMW0
#undef TILE_BODY
}

// -------- MFMA flash attention: 64 q/block, single-buffer async staging, 4 blk/CU --------
__global__ __launch_bounds__(256, 4) void attn_mfma(
    const unsigned short* __restrict__ qhl,
    const unsigned short* __restrict__ khl,   // fragment-ordered tiles
    const unsigned short* __restrict__ vt,    // fragment-ordered tiles
    const int* __restrict__ mask,
    float* __restrict__ out)
{
  __shared__ unsigned short Ks[8192];
  __shared__ unsigned short Vs[4096];
  __shared__ unsigned short Pw[4][1024];
  __shared__ float msks[1024];

  const int tid  = threadIdx.x;
  const int wave = tid >> 6;
  const int lane = tid & 63;
  const int l16  = lane & 15;
  const int quad = lane >> 4;

  // bh fastest (stride 128 ≡ 0 mod 8) -> all q-tiles of one bh on the same XCD
  const int bh = blockIdx.x & 127;
  const int qt = blockIdx.x >> 7;
  const int bb = bh >> 4;
  const int q0 = qt * 64;

  const unsigned short* kplane = khl + (size_t)bh * 131072;
  const unsigned short* vplane = vt  + (size_t)bh * 65536;

  // mask row preload (once)
  {
    int4 mv = *(const int4*)&mask[bb * Sdim + tid * 4];
    msks[tid * 4 + 0] = mv.x ? 1.f : 0.f;
    msks[tid * 4 + 1] = mv.y ? 1.f : 0.f;
    msks[tid * 4 + 2] = mv.z ? 1.f : 0.f;
    msks[tid * 4 + 3] = mv.w ? 1.f : 0.f;
  }

  // Q fragments direct from global
  bf16x8 qf[4];
  {
    int row = q0 + wave * 16 + l16;
    const unsigned short* src = qhl + ((size_t)bh * Sdim + row) * 128;
    #pragma unroll
    for (int kk = 0; kk < 4; ++kk)
      qf[kk] = *(const bf16x8*)&src[kk * 32 + quad * 8];
  }

  f32x4 O[4] = {{0.f,0.f,0.f,0.f},{0.f,0.f,0.f,0.f},{0.f,0.f,0.f,0.f},{0.f,0.f,0.f,0.f}};
  float mrow[4] = {-INFINITY, -INFINITY, -INFINITY, -INFINITY};
  float lrow[4] = {0.f, 0.f, 0.f, 0.f};

  #pragma unroll 1
  for (int kt = 0; kt < 16; ++kt) {
    __syncthreads();   // previous tile's readers done (also orders msks on kt=0)
    {
      const unsigned short* ksrc = kplane + (size_t)kt * 8192;
      const unsigned short* vsrc = vplane + (size_t)kt * 4096;
      #pragma unroll
      for (int r = 0; r < 4; ++r)
        async16(&Ks[(r * 256 + tid) * 8], &ksrc[(size_t)(r * 256 + tid) * 8]);
      #pragma unroll
      for (int r = 0; r < 2; ++r)
        async16(&Vs[(r * 256 + tid) * 8], &vsrc[(size_t)(r * 256 + tid) * 8]);
    }
    __syncthreads();   // staged tile visible (drains vmcnt)

    // QK^T: 3-term split (hi·hi + lo·hi + hi·lo); conflict-free lane-contiguous reads
    f32x4 sc[4];
    #pragma unroll
    for (int ns = 0; ns < 4; ++ns) {
      f32x4 c = {0.f, 0.f, 0.f, 0.f};
      bf16x8 kf0 = *(const bf16x8*)&Ks[((ns * 4 + 0) * 64 + lane) * 8];
      bf16x8 kf1 = *(const bf16x8*)&Ks[((ns * 4 + 1) * 64 + lane) * 8];
      bf16x8 kf2 = *(const bf16x8*)&Ks[((ns * 4 + 2) * 64 + lane) * 8];
      bf16x8 kf3 = *(const bf16x8*)&Ks[((ns * 4 + 3) * 64 + lane) * 8];
      c = __builtin_amdgcn_mfma_f32_16x16x32_bf16(qf[0], kf0, c, 0, 0, 0);
      c = __builtin_amdgcn_mfma_f32_16x16x32_bf16(qf[1], kf1, c, 0, 0, 0);
      c = __builtin_amdgcn_mfma_f32_16x16x32_bf16(qf[2], kf0, c, 0, 0, 0);
      c = __builtin_amdgcn_mfma_f32_16x16x32_bf16(qf[3], kf1, c, 0, 0, 0);
      c = __builtin_amdgcn_mfma_f32_16x16x32_bf16(qf[0], kf2, c, 0, 0, 0);
      c = __builtin_amdgcn_mfma_f32_16x16x32_bf16(qf[1], kf3, c, 0, 0, 0);
      sc[ns] = c;
    }

    // mask + scale, row max
    float rmax[4] = {-INFINITY, -INFINITY, -INFINITY, -INFINITY};
    #pragma unroll
    for (int ns = 0; ns < 4; ++ns) {
      float mk = msks[kt * 64 + ns * 16 + l16];
      #pragma unroll
      for (int r = 0; r < 4; ++r) {
        float s = (mk != 0.f) ? -10000.f : sc[ns][r] * 8.f;
        sc[ns][r] = s;
        rmax[r] = fmaxf(rmax[r], s);
      }
    }
    #pragma unroll
    for (int r = 0; r < 4; ++r) {
      float v = rmax[r];
      v = fmaxf(v, __shfl_xor(v, 1, 16));
      v = fmaxf(v, __shfl_xor(v, 2, 16));
      v = fmaxf(v, __shfl_xor(v, 4, 16));
      v = fmaxf(v, __shfl_xor(v, 8, 16));
      rmax[r] = v;
    }

    float alpha[4];
    #pragma unroll
    for (int r = 0; r < 4; ++r) {
      float mn = fmaxf(mrow[r], rmax[r]);
      alpha[r] = __expf(mrow[r] - mn);
      mrow[r] = mn;
      lrow[r] *= alpha[r];
    }
    #pragma unroll
    for (int d = 0; d < 4; ++d)
      #pragma unroll
      for (int r = 0; r < 4; ++r) O[d][r] *= alpha[r];

    // exp, row-sum, write P (bf16) to per-wave LDS in A-fragment order
    float rsum[4] = {0.f, 0.f, 0.f, 0.f};
    #pragma unroll
    for (int ns = 0; ns < 4; ++ns) {
      int key = ns * 16 + l16;
      int cbase = (((key >> 5) * 4 + ((key >> 3) & 3)) * 16 + quad * 4) * 8 + (key & 7);
      #pragma unroll
      for (int r = 0; r < 4; ++r) {
        float p = __expf(sc[ns][r] - mrow[r]);
        rsum[r] += p;
        Pw[wave][cbase + r * 8] = f2bf(p);
      }
    }
    #pragma unroll
    for (int r = 0; r < 4; ++r) {
      float v = rsum[r];
      v += __shfl_xor(v, 1, 16);
      v += __shfl_xor(v, 2, 16);
      v += __shfl_xor(v, 4, 16);
      v += __shfl_xor(v, 8, 16);
      lrow[r] += v;
    }

    // P·V (wave-local; lane-contiguous reads)
    bf16x8 pf[2];
    #pragma unroll
    for (int kk = 0; kk < 2; ++kk)
      pf[kk] = *(const bf16x8*)&Pw[wave][((kk * 4 + quad) * 16 + l16) * 8];
    #pragma unroll
    for (int d = 0; d < 4; ++d)
      #pragma unroll
      for (int kk = 0; kk < 2; ++kk) {
        bf16x8 vf = *(const bf16x8*)&Vs[((d * 2 + kk) * 64 + lane) * 8];
        O[d] = __builtin_amdgcn_mfma_f32_16x16x32_bf16(pf[kk], vf, O[d], 0, 0, 0);
      }
  }

  // epilogue
  const int h = bh & 15;
  #pragma unroll
  for (int r = 0; r < 4; ++r) {
    float inv = 1.f / lrow[r];
    int q = q0 + wave * 16 + quad * 4 + r;
    float* dst = out + ((size_t)bb * Sdim + q) * Hdim + h * HDd;
    #pragma unroll
    for (int d = 0; d < 4; ++d)
      dst[d * 16 + l16] = O[d][r] * inv;
  }
}

extern "C" void kernel_launch(void* const* d_in, const int* in_sizes, int n_in,
                              void* d_out, int out_size, void* d_ws, size_t ws_size,
                              hipStream_t stream) {
  const float* hs   = (const float*)d_in[0];
  const int*   mask = (const int*)d_in[1];
  const float* w    = (const float*)d_in[2];
  const float* bias = (const float*)d_in[3];
  float* out = (float*)d_out;
  unsigned short* ws = (unsigned short*)d_ws;
  unsigned short* ao = (unsigned short*)d_out;   // A hi/lo scratch, overwritten by attn

  convert_AW<<<4096 + (N3H / 64) * (1024 / 64), 256, 0, stream>>>(hs, w, ao, ws);

  qkv_mfma<<<dim3(256), 512, 0, stream>>>(ao, ws, bias, ws);

  attn_mfma<<<Bdim * NHd * (Sdim / 64), 256, 0, stream>>>(
      ws + Q_OFF, ws + K_OFF, ws + V_OFF, mask, out);
}